// Round 1
// baseline (70.933 us; speedup 1.0000x reference)
//
#include <hip/hip_runtime.h>
#include <hip/hip_bf16.h>

// CWAUC-H loss: closed-form O(B) reduction of the reference's O(B^2) pairwise penalty.
//
// Reference math:
//   s  = sigmoid(output[:,0])                       (fp32)
//   penalty = sum_{i:lab=0, j:lab=1} (1 - (s_j - s_i))^2 / (Npos*Nneg) / LAMB
//   With LAMB=2, (1 + s_i - s_j)^2 expands:
//     sum = Npos*Σ_neg(1+s)^2 - 2*Σ_neg(1+s)*Σ_pos(s) + Nneg*Σ_pos(s^2)
//   outs2 = sigmoid(s)   (double sigmoid!)
//   fpcls = -(Nneg/B)*mean(lab*log(outs2+EPS)) - (Npos/B)*mean((1-lab)*log(1-outs2+EPS))
//   out = (fpcls + penalty, penalty)
//
// Accumulate in fp64 so the closed form is exact w.r.t. the fp32 per-element s.

#define NB    8192
#define NTHR  1024

__global__ __launch_bounds__(NTHR) void cwauc_kernel(const float* __restrict__ outp,
                                                     const float* __restrict__ labels,
                                                     float* __restrict__ res) {
    const int tid = threadIdx.x;

    // 8 accumulators: cntPos, cntNeg, Σpos s, Σpos s², Σneg (1+s), Σneg (1+s)², Σ lab*log(sig(s)+eps), Σ (1-lab)*log(1-sig(s)+eps)
    double cPos = 0.0, cNeg = 0.0;
    double sp1 = 0.0, sp2 = 0.0;
    double sn1 = 0.0, sn2 = 0.0;
    double lp  = 0.0, ln  = 0.0;

    for (int i = tid; i < NB; i += NTHR) {
        // output is (B,2) row-major; we need column 0 -> element 2*i
        float x   = outp[2 * i];
        float lab = labels[i];

        float s  = 1.0f / (1.0f + __expf(-x) * 0.0f + expf(-x));  // keep plain expf (accuracy)
        s = 1.0f / (1.0f + expf(-x));
        float s2 = 1.0f / (1.0f + expf(-s));                      // sigmoid(sigmoid(x))

        if (lab == 1.0f) {
            cPos += 1.0;
            sp1  += (double)s;
            sp2  += (double)s * (double)s;
            lp   += log((double)s2 + 1e-32);
        } else {  // lab == 0.0f (labels are exactly 0/1)
            cNeg += 1.0;
            double c = 1.0 + (double)s;
            sn1  += c;
            sn2  += c * c;
            ln   += log(1.0 - (double)s2 + 1e-32);
        }
    }

    double acc[8] = {cPos, cNeg, sp1, sp2, sn1, sn2, lp, ln};

    // wave-level (64-lane) butterfly reduce
    #pragma unroll
    for (int off = 32; off > 0; off >>= 1) {
        #pragma unroll
        for (int k = 0; k < 8; ++k)
            acc[k] += __shfl_down(acc[k], off, 64);
    }

    // cross-wave reduce via LDS (16 waves)
    __shared__ double lds[NTHR / 64][8];
    const int wave = tid >> 6;
    const int lane = tid & 63;
    if (lane == 0) {
        #pragma unroll
        for (int k = 0; k < 8; ++k) lds[wave][k] = acc[k];
    }
    __syncthreads();

    if (tid == 0) {
        double tot[8];
        #pragma unroll
        for (int k = 0; k < 8; ++k) {
            double t = 0.0;
            for (int w = 0; w < NTHR / 64; ++w) t += lds[w][k];
            tot[k] = t;
        }
        const double nPos = tot[0], nNeg = tot[1];
        const double Sp1 = tot[2], Sp2 = tot[3];
        const double Sn1 = tot[4], Sn2 = tot[5];
        const double Lp  = tot[6], Ln  = tot[7];

        const double invB = 1.0 / (double)NB;

        // closed-form pairwise sum
        const double pairSum = nPos * Sn2 - 2.0 * Sn1 * Sp1 + nNeg * Sp2;
        const double penalty = pairSum / (nPos * nNeg) / 2.0;   // / LAMB

        // weighted BCE on double-sigmoid
        const double fpcls = -(nNeg * invB) * (Lp * invB) - (nPos * invB) * (Ln * invB);

        const double cls = fpcls + penalty;                      // ALPHA = 1

        res[0] = (float)cls;
        res[1] = (float)penalty;                                 // ALPHA * penalty
    }
}

extern "C" void kernel_launch(void* const* d_in, const int* in_sizes, int n_in,
                              void* d_out, int out_size, void* d_ws, size_t ws_size,
                              hipStream_t stream) {
    const float* outp   = (const float*)d_in[0];   // (8192, 2) fp32
    const float* labels = (const float*)d_in[1];   // (8192, 1) fp32
    float* res = (float*)d_out;                    // [cls, alpha*penalty]

    cwauc_kernel<<<1, NTHR, 0, stream>>>(outp, labels, res);
}

// Round 2
// 61.380 us; speedup vs baseline: 1.1557x; 1.1557x over previous
//
#include <hip/hip_runtime.h>
#include <hip/hip_bf16.h>

// CWAUC-H loss — closed-form O(B) collapse of the O(B^2) pairwise penalty.
//
//   s  = sigmoid(output[:,0]); c_i = 1+s_i (negatives)
//   pairSum = Npos*Σneg c² − 2*(Σneg c)*(Σpos s) + Nneg*Σpos s²
//   penalty = pairSum / (Npos*Nneg) / LAMB            (LAMB=2)
//   s2 = sigmoid(s)  (reference applies sigmoid twice)
//   fpcls = −(Nneg/B)·(Σpos log s2)/B − (Npos/B)·(Σneg log(1−s2))/B
//   out = (fpcls + penalty, penalty)                  (ALPHA=1)
//
// R1: inner loop all-fp32 (logf/expf are HW-accelerated; fp64 log was the
// R0 bottleneck — ~8192 software f64 logs on one CU). Per-thread partials
// in fp32 (≤8 summands each, error ~1e-7 rel); fp64 only for the cross-lane
// reduction and final algebra. EPS=1e-32 is sub-ulp for s2∈(0.27,0.73) so
// logf(s2) ≡ logf(s2+EPS).

#define NB    8192
#define NTHR  1024
#define PER   (NB / NTHR)   // 8 elements per thread

__global__ __launch_bounds__(NTHR, 1) void cwauc_kernel(const float* __restrict__ outp,
                                                        const float* __restrict__ labels,
                                                        float* __restrict__ res) {
    const int tid = threadIdx.x;
    const float2* __restrict__ outp2 = (const float2*)outp;

    // fp32 per-thread partials (7 accs; cNeg = NB - cPos derived at the end)
    float cPos = 0.f;
    float sp1 = 0.f, sp2 = 0.f;     // Σpos s, Σpos s²
    float sn1 = 0.f, sn2 = 0.f;     // Σneg (1+s), Σneg (1+s)²
    float lp  = 0.f, ln  = 0.f;     // Σpos log(s2), Σneg log(1−s2)

    #pragma unroll
    for (int u = 0; u < PER; ++u) {
        const int i = tid + u * NTHR;           // coalesced
        const float x   = outp2[i].x;           // output[:,0]
        const float lab = labels[i];

        const float s  = 1.0f / (1.0f + expf(-x));
        const float s2 = 1.0f / (1.0f + expf(-s));

        if (lab == 1.0f) {
            cPos += 1.0f;
            sp1  += s;
            sp2  += s * s;
            lp   += logf(s2);
        } else {
            const float c = 1.0f + s;
            sn1  += c;
            sn2  += c * c;
            ln   += logf(1.0f - s2);
        }
    }

    // promote to fp64 for the cross-lane reduction
    double acc[7] = {(double)cPos, (double)sp1, (double)sp2,
                     (double)sn1,  (double)sn2, (double)lp, (double)ln};

    #pragma unroll
    for (int off = 32; off > 0; off >>= 1) {
        #pragma unroll
        for (int k = 0; k < 7; ++k)
            acc[k] += __shfl_down(acc[k], off, 64);
    }

    __shared__ double lds[NTHR / 64][7];
    const int wave = tid >> 6;
    const int lane = tid & 63;
    if (lane == 0) {
        #pragma unroll
        for (int k = 0; k < 7; ++k) lds[wave][k] = acc[k];
    }
    __syncthreads();

    if (tid == 0) {
        double tot[7];
        #pragma unroll
        for (int k = 0; k < 7; ++k) {
            double t = lds[0][k];
            for (int w = 1; w < NTHR / 64; ++w) t += lds[w][k];
            tot[k] = t;
        }
        const double nPos = tot[0];
        const double nNeg = (double)NB - nPos;
        const double Sp1 = tot[1], Sp2 = tot[2];
        const double Sn1 = tot[3], Sn2 = tot[4];
        const double Lp  = tot[5], Ln  = tot[6];

        const double invB = 1.0 / (double)NB;

        const double pairSum = nPos * Sn2 - 2.0 * Sn1 * Sp1 + nNeg * Sp2;
        const double penalty = pairSum / (nPos * nNeg) * 0.5;    // / LAMB

        const double fpcls = -(nNeg * invB) * (Lp * invB) - (nPos * invB) * (Ln * invB);

        res[0] = (float)(fpcls + penalty);    // ALPHA = 1
        res[1] = (float)penalty;
    }
}

extern "C" void kernel_launch(void* const* d_in, const int* in_sizes, int n_in,
                              void* d_out, int out_size, void* d_ws, size_t ws_size,
                              hipStream_t stream) {
    const float* outp   = (const float*)d_in[0];   // (8192, 2) fp32
    const float* labels = (const float*)d_in[1];   // (8192, 1) fp32
    float* res = (float*)d_out;                    // [cls, alpha*penalty]

    cwauc_kernel<<<1, NTHR, 0, stream>>>(outp, labels, res);
}

// Round 3
// 60.259 us; speedup vs baseline: 1.1771x; 1.0186x over previous
//
#include <hip/hip_runtime.h>
#include <hip/hip_bf16.h>

// CWAUC-H loss — closed-form O(B) collapse of the O(B^2) pairwise penalty.
//
//   s  = sigmoid(output[:,0]); for negatives c_i = 1+s_i
//   pairSum = Npos*Σneg c² − 2*(Σneg c)*(Σpos s) + Nneg*Σpos s²
//   penalty = pairSum / (Npos*Nneg) / LAMB            (LAMB=2)
//   s2 = sigmoid(s)   (reference applies sigmoid twice)
//   fpcls = −(Nneg/B)·(Σpos log s2)/B − (Npos/B)·(Σneg log(1−s2))/B
//   out = (fpcls + penalty, penalty)                  (ALPHA=1)
//
// R2: branchless inner loop —
//   t   = neg + s          (s for pos, 1+s for neg; t² computed once)
//   arg = neg + (m−neg)·s2 (s2 for pos, 1−s2 for neg) → ONE logf/elem (was 2
//         under exec-mask divergence), masked into lp/ln.
//   __expf/__logf HW intrinsics (v_exp_f32/v_log_f32; ~1e-7 rel err, s2 is
//   bounded in (0.27,0.73) so log args are far from 0 — EPS=1e-32 is sub-ulp).
// fp64 only for cross-lane reduction + final algebra.

#define NB    8192
#define NTHR  1024
#define PER   (NB / NTHR)   // 8 elements per thread

__global__ __launch_bounds__(NTHR, 1) void cwauc_kernel(const float* __restrict__ outp,
                                                        const float* __restrict__ labels,
                                                        float* __restrict__ res) {
    const int tid = threadIdx.x;
    const float2* __restrict__ outp2 = (const float2*)outp;

    float cPos = 0.f;
    float sp1 = 0.f, sp2 = 0.f;     // Σpos s, Σpos s²
    float sn1 = 0.f, sn2 = 0.f;     // Σneg (1+s), Σneg (1+s)²
    float lp  = 0.f, ln  = 0.f;     // Σpos log(s2), Σneg log(1−s2)

    #pragma unroll
    for (int u = 0; u < PER; ++u) {
        const int i = tid + u * NTHR;           // coalesced
        const float x = outp2[i].x;             // output[:,0]
        const float m = labels[i];              // 1.0 pos / 0.0 neg
        const float neg = 1.0f - m;

        const float s  = 1.0f / (1.0f + __expf(-x));
        const float s2 = 1.0f / (1.0f + __expf(-s));

        const float t  = neg + s;               // s (pos) or 1+s (neg)
        const float t2 = t * t;
        const float la = __logf(fmaf(m - neg, s2, neg));  // log s2 (pos) / log(1-s2) (neg)

        cPos += m;
        sp1  = fmaf(m,   t,  sp1);
        sp2  = fmaf(m,   t2, sp2);
        sn1  = fmaf(neg, t,  sn1);
        sn2  = fmaf(neg, t2, sn2);
        lp   = fmaf(m,   la, lp);
        ln   = fmaf(neg, la, ln);
    }

    // promote to fp64 for the cross-lane reduction
    double acc[7] = {(double)cPos, (double)sp1, (double)sp2,
                     (double)sn1,  (double)sn2, (double)lp, (double)ln};

    #pragma unroll
    for (int off = 32; off > 0; off >>= 1) {
        #pragma unroll
        for (int k = 0; k < 7; ++k)
            acc[k] += __shfl_down(acc[k], off, 64);
    }

    __shared__ double lds[NTHR / 64][7];
    const int wave = tid >> 6;
    const int lane = tid & 63;
    if (lane == 0) {
        #pragma unroll
        for (int k = 0; k < 7; ++k) lds[wave][k] = acc[k];
    }
    __syncthreads();

    if (tid == 0) {
        double tot[7];
        #pragma unroll
        for (int k = 0; k < 7; ++k) {
            double t = lds[0][k];
            for (int w = 1; w < NTHR / 64; ++w) t += lds[w][k];
            tot[k] = t;
        }
        const double nPos = tot[0];
        const double nNeg = (double)NB - nPos;
        const double Sp1 = tot[1], Sp2 = tot[2];
        const double Sn1 = tot[3], Sn2 = tot[4];
        const double Lp  = tot[5], Ln  = tot[6];

        const double invB = 1.0 / (double)NB;

        const double pairSum = nPos * Sn2 - 2.0 * Sn1 * Sp1 + nNeg * Sp2;
        const double penalty = pairSum / (nPos * nNeg) * 0.5;    // / LAMB

        const double fpcls = -(nNeg * invB) * (Lp * invB) - (nPos * invB) * (Ln * invB);

        res[0] = (float)(fpcls + penalty);    // ALPHA = 1
        res[1] = (float)penalty;
    }
}

extern "C" void kernel_launch(void* const* d_in, const int* in_sizes, int n_in,
                              void* d_out, int out_size, void* d_ws, size_t ws_size,
                              hipStream_t stream) {
    const float* outp   = (const float*)d_in[0];   // (8192, 2) fp32
    const float* labels = (const float*)d_in[1];   // (8192, 1) fp32
    float* res = (float*)d_out;                    // [cls, alpha*penalty]

    cwauc_kernel<<<1, NTHR, 0, stream>>>(outp, labels, res);
}